// Round 11
// baseline (230.843 us; speedup 1.0000x reference)
//
#include <hip/hip_runtime.h>
#include <hip/hip_bf16.h>

typedef unsigned short u16;
typedef unsigned long long u64;
typedef short short8_t __attribute__((ext_vector_type(8)));
typedef float floatx4 __attribute__((ext_vector_type(4)));

constexpr int NT = 4096, H = 128, CAP = 64;
constexpr int GRID = 512, BLK = 256, GSTRIDE = GRID * BLK;
constexpr int ROWS = 8;                     // rows per block; 2 blocks/CU overlap

// bf16 weight arena element offsets (layer-0 qkv region unused: prep reads f32)
constexpr int OFF_QKV  = 0;                 // 4*384*128
constexpr int OFF_AO   = 196608;            // 4*128*128
constexpr int OFF_F1   = 262144;            // 4*256*128
constexpr int OFF_F2   = 393216;            // 4*128*256
constexpr int OFF_LAT1 = 524288;            // 128*128
constexpr int OFF_B1   = 540672;            // 64*128
constexpr int OFF_LAT2 = 548864;            // 16*128
constexpr int W_TOTAL  = 550912;

__device__ __forceinline__ float bfu(u16 u) { return __uint_as_float(((unsigned)u) << 16); }
__device__ __forceinline__ u16 f2bf(float f) {
  unsigned u = __float_as_uint(f);
  u += 0x7fffu + ((u >> 16) & 1u);          // RNE
  return (u16)(u >> 16);
}
__device__ __forceinline__ void unpack8(uint4 u, float* f) {
  f[0] = __uint_as_float(u.x << 16); f[1] = __uint_as_float(u.x & 0xffff0000u);
  f[2] = __uint_as_float(u.y << 16); f[3] = __uint_as_float(u.y & 0xffff0000u);
  f[4] = __uint_as_float(u.z << 16); f[5] = __uint_as_float(u.z & 0xffff0000u);
  f[6] = __uint_as_float(u.w << 16); f[7] = __uint_as_float(u.w & 0xffff0000u);
}
__device__ __forceinline__ short8_t cvt8(const float* bp) {   // f32 row -> bf16 frag
  const float4 f0 = *(const float4*)bp, f1 = *(const float4*)(bp + 4);
  short8_t r;
  r[0] = (short)f2bf(f0.x); r[1] = (short)f2bf(f0.y);
  r[2] = (short)f2bf(f0.z); r[3] = (short)f2bf(f0.w);
  r[4] = (short)f2bf(f1.x); r[5] = (short)f2bf(f1.y);
  r[6] = (short)f2bf(f1.z); r[7] = (short)f2bf(f1.w);
  return r;
}

struct Prm {
  const float *xr, *in_w, *in_b, *ln1_s, *ln1_b, *qkv_w, *qkv_b, *ao_w, *ao_b,
              *ln2_s, *ln2_b, *f1_w, *f1_b, *f2_w, *f2_b, *lat1_w, *lat1_b,
              *lat2_w, *lat2_b, *b1_w, *b1_b, *b2_w, *b2_b;
  u16* W; u16* QKV0; u16* QKV1; float* Xg; int* NI; int* NC; float* out;
};

// ======================= K0: prep + qkv layer 0 =======================
__global__ __launch_bounds__(BLK, 2) void prep_kernel(Prm p) {
  const int t = threadIdx.x, bid = blockIdx.x;
  const int lane = t & 63, w = t >> 6;          // 4 waves
  const int lr = lane & 15, quad = lane >> 4;
  const int gtid = bid * BLK + t;
  const int r0 = bid * ROWS;
  const floatx4 FZ = {0.f, 0.f, 0.f, 0.f};

  __shared__ float Xs[ROWS][132];
  __shared__ union {
    unsigned long long words[ROWS][64];
    struct { u16 A16[ROWS][152]; } g;
    u16 QS[ROWS][384];
  } sm;

  // wconv (skip unused layer-0 qkv region)
  for (int i = 49152 + gtid; i < W_TOTAL; i += GSTRIDE) {
    float v;
    if      (i < OFF_AO)   v = p.qkv_w[i];
    else if (i < OFF_F1)   v = p.ao_w[i - OFF_AO];
    else if (i < OFF_F2)   v = p.f1_w[i - OFF_F1];
    else if (i < OFF_LAT1) v = p.f2_w[i - OFF_F2];
    else if (i < OFF_B1)   v = p.lat1_w[i - OFF_LAT1];
    else if (i < OFF_LAT2) v = p.b1_w[i - OFF_B1];
    else                   v = p.lat2_w[i - OFF_LAT2];
    p.W[i] = f2bf(v);
  }
  // in_proj for own 8 rows -> Xs + Xg
  for (int i = t; i < ROWS * H; i += BLK) {
    const int r = i >> 7, c = i & 127;
    const float* xp = p.xr + (size_t)(r0 + r) * 16;
    const float* wp = p.in_w + c * 16;
    float acc = p.in_b[c];
#pragma unroll
    for (int k = 0; k < 16; ++k) acc += xp[k] * wp[k];
    Xs[r][c] = acc;
    p.Xg[(size_t)(r0 + r) * H + c] = acc;
  }
  // neighbor lists for own 8 rows -> global NI/NC
  {
    double qe[ROWS], qp_[ROWS];
#pragma unroll
    for (int j = 0; j < ROWS; ++j) {
      qe[j]  = (double)p.xr[(r0 + j) * 16 + 1] * 5.24 - 2.62;
      qp_[j] = (double)p.xr[(r0 + j) * 16 + 2] * 6.2832 - 3.1416;
    }
    for (int c = 0; c < 16; ++c) {              // 16 chunks of 256 keys
      const int k = c * 256 + t;
      const double ke = (double)p.xr[k * 16 + 1] * 5.24 - 2.62;
      const double kp = (double)p.xr[k * 16 + 2] * 6.2832 - 3.1416;
#pragma unroll
      for (int j = 0; j < ROWS; ++j) {
        const double de = qe[j] - ke;
        double dp = qp_[j] - kp;
        dp -= 6.283185307179586 * rint(dp * 0.15915494309189535);  // atan2 wrap
        const unsigned long long bm = __ballot((de * de + dp * dp) <= 0.04);
        if (lane == 0) sm.words[j][c * 4 + w] = bm;   // idx i covers keys [i*64,+64)
      }
    }
    __syncthreads();
    for (int u = 0; u < 2; ++u) {               // each wave compacts 2 q's
      const int lq = w * 2 + u;
      unsigned long long m = sm.words[lq][lane];
      const int cnt = __popcll(m);
      int incl = cnt;
#pragma unroll
      for (int off = 1; off < 64; off <<= 1) {
        const int n = __shfl_up(incl, off);
        if (lane >= off) incl += n;
      }
      int pos = incl - cnt;
      const int qq = r0 + lq;
      const int kbase = lane * 64;
      while (m) {
        const int b = __builtin_ctzll(m);
        m &= m - 1;
        if (pos < CAP) p.NI[qq * CAP + pos] = kbase + b;
        ++pos;
      }
      if (lane == 63) p.NC[qq] = incl > CAP ? CAP : incl;
    }
    __syncthreads();
  }
  // LN1(0) -> A16
  {
    const int r = t >> 5, j0 = (t & 31) * 4;
    const float4 xv = *(const float4*)&Xs[r][j0];
    float v0 = xv.x, v1 = xv.y, v2 = xv.z, v3 = xv.w;
    float s = v0 + v1 + v2 + v3;
    float ss = v0 * v0 + v1 * v1 + v2 * v2 + v3 * v3;
#pragma unroll
    for (int off = 1; off <= 16; off <<= 1) {
      s += __shfl_xor(s, off); ss += __shfl_xor(ss, off);
    }
    const float mean = s * (1.f / 128.f);
    const float rstd = rsqrtf(ss * (1.f / 128.f) - mean * mean + 1e-5f);
    v0 = (v0 - mean) * rstd * p.ln1_s[j0]     + p.ln1_b[j0];
    v1 = (v1 - mean) * rstd * p.ln1_s[j0 + 1] + p.ln1_b[j0 + 1];
    v2 = (v2 - mean) * rstd * p.ln1_s[j0 + 2] + p.ln1_b[j0 + 2];
    v3 = (v3 - mean) * rstd * p.ln1_s[j0 + 3] + p.ln1_b[j0 + 3];
    uint2 pk;
    pk.x = (unsigned)f2bf(v0) | ((unsigned)f2bf(v1) << 16);
    pk.y = (unsigned)f2bf(v2) | ((unsigned)f2bf(v3) << 16);
    *(uint2*)&sm.g.A16[r][j0] = pk;
  }
  __syncthreads();
  // qkv0 from f32 weights (register-convert), M=8 half-tile
  {
    const int c0 = w * 96;
    floatx4 acc[6];
#pragma unroll
    for (int i = 0; i < 6; ++i) acc[i] = FZ;
#pragma unroll
    for (int k0 = 0; k0 < 128; k0 += 32) {
      short8_t a = *(const short8_t*)&sm.g.A16[lr & 7][k0 + quad * 8];
#pragma unroll
      for (int i = 0; i < 6; ++i) {
        short8_t b = cvt8(&p.qkv_w[(size_t)(c0 + i * 16 + lr) * 128 + k0 + quad * 8]);
        acc[i] = __builtin_amdgcn_mfma_f32_16x16x32_bf16(a, b, acc[i], 0, 0, 0);
      }
    }
    __syncthreads();
    if (quad < 2) {
#pragma unroll
      for (int i = 0; i < 6; ++i) {
        const int col = c0 + i * 16 + lr;
        const float bv = p.qkv_b[col];
#pragma unroll
        for (int r = 0; r < 4; ++r)
          sm.QS[quad * 4 + r][col] = f2bf(acc[i][r] + bv);
      }
    }
    __syncthreads();
    u64* d64 = (u64*)(p.QKV0 + (size_t)r0 * 384);
    const u64* s64 = (const u64*)&sm.QS[0][0];
    for (int j = t; j < 768; j += BLK) d64[j] = s64[j];   // 8 rows*384 u16 = 768 u64
  }
}

// ============ K1..K4: one transformer layer (+qkv next / heads) ============
__global__ __launch_bounds__(BLK, 2) void layer_kernel(Prm p, int l,
                                                       const u16* __restrict__ qsrc,
                                                       u16* __restrict__ qdst) {
  const int t = threadIdx.x, bid = blockIdx.x;
  const int lane = t & 63, w = t >> 6;          // 4 waves
  const int lr = lane & 15, quad = lane >> 4;
  const int r0 = bid * ROWS;
  const floatx4 FZ = {0.f, 0.f, 0.f, 0.f};

  __shared__ float Xs[ROWS][132];
  __shared__ int NIs[ROWS][CAP];
  __shared__ int NCs[ROWS];
  __shared__ union {
    struct { u16 A16[ROWS][152]; u16 FF1[ROWS][280]; } g;
    u16 QS[ROWS][384];
  } sm;

  // load block state
  {
    const int r = t >> 5, j0 = (t & 31) * 4;
    *(float4*)&Xs[r][j0] = *(const float4*)&p.Xg[(size_t)(r0 + r) * H + j0];
    for (int j = t; j < ROWS * CAP; j += BLK) (&NIs[0][0])[j] = p.NI[r0 * CAP + j];
    if (t < ROWS) NCs[t] = p.NC[r0 + t];
  }

  auto stage_x = [&](const float* sc, const float* bi, bool do_ln) {
    const int r = t >> 5, j0 = (t & 31) * 4;
    const float4 xv = *(const float4*)&Xs[r][j0];
    float v0 = xv.x, v1 = xv.y, v2 = xv.z, v3 = xv.w;
    if (do_ln) {
      float s = v0 + v1 + v2 + v3;
      float ss = v0 * v0 + v1 * v1 + v2 * v2 + v3 * v3;
#pragma unroll
      for (int off = 1; off <= 16; off <<= 1) {
        s += __shfl_xor(s, off); ss += __shfl_xor(ss, off);
      }
      const float mean = s * (1.f / 128.f);
      const float rstd = rsqrtf(ss * (1.f / 128.f) - mean * mean + 1e-5f);
      v0 = (v0 - mean) * rstd * sc[j0]     + bi[j0];
      v1 = (v1 - mean) * rstd * sc[j0 + 1] + bi[j0 + 1];
      v2 = (v2 - mean) * rstd * sc[j0 + 2] + bi[j0 + 2];
      v3 = (v3 - mean) * rstd * sc[j0 + 3] + bi[j0 + 3];
    }
    uint2 pk;
    pk.x = (unsigned)f2bf(v0) | ((unsigned)f2bf(v1) << 16);
    pk.y = (unsigned)f2bf(v2) | ((unsigned)f2bf(v3) << 16);
    *(uint2*)&sm.g.A16[r][j0] = pk;
  };
  __syncthreads();

  // --- attention: 64 (q,h) pairs, 4 threads/pair over neighbors ---
  {
    const int pr = t >> 2, sub = t & 3;
    const int lq = pr >> 3, h = pr & 7;
    const u16* qp = qsrc + (size_t)(r0 + lq) * 384 + h * 16;
    float qv[16];
    { uint4 a = *(const uint4*)qp, b = *(const uint4*)(qp + 8);
      unpack8(a, qv); unpack8(b, qv + 8); }
#pragma unroll
    for (int d = 0; d < 16; ++d) qv[d] *= 0.25f;        // 1/sqrt(HD)
    float o[16];
#pragma unroll
    for (int d = 0; d < 16; ++d) o[d] = 0.f;
    float se = 0.f;
    const int cnt = NCs[lq];
    for (int i = sub; i < cnt; i += 4) {
      const int nb = NIs[lq][i];
      const u16* kp = qsrc + (size_t)nb * 384 + 128 + h * 16;
      float kv[16], vv[16];
      { uint4 a = *(const uint4*)kp;         uint4 b = *(const uint4*)(kp + 8);
        unpack8(a, kv); unpack8(b, kv + 8); }
      { uint4 a = *(const uint4*)(kp + 128); uint4 b = *(const uint4*)(kp + 136);
        unpack8(a, vv); unpack8(b, vv + 8); }
      float s0 = 0.f, s1 = 0.f, s2 = 0.f, s3 = 0.f;
#pragma unroll
      for (int d = 0; d < 16; d += 4) {
        s0 += qv[d] * kv[d];         s1 += qv[d + 1] * kv[d + 1];
        s2 += qv[d + 2] * kv[d + 2]; s3 += qv[d + 3] * kv[d + 3];
      }
      const float e = expf((s0 + s1) + (s2 + s3));      // |s|<~0.5, no max-sub
      se += e;
#pragma unroll
      for (int d = 0; d < 16; ++d) o[d] += e * vv[d];
    }
#pragma unroll
    for (int d = 0; d < 16; ++d) o[d] += __shfl_xor(o[d], 1);
    se += __shfl_xor(se, 1);
#pragma unroll
    for (int d = 0; d < 16; ++d) o[d] += __shfl_xor(o[d], 2);
    se += __shfl_xor(se, 2);
    if (sub == 0) {
      const float inv = 1.f / se;
      uint4 w0, w1;
      w0.x = (unsigned)f2bf(o[0] * inv)  | ((unsigned)f2bf(o[1] * inv) << 16);
      w0.y = (unsigned)f2bf(o[2] * inv)  | ((unsigned)f2bf(o[3] * inv) << 16);
      w0.z = (unsigned)f2bf(o[4] * inv)  | ((unsigned)f2bf(o[5] * inv) << 16);
      w0.w = (unsigned)f2bf(o[6] * inv)  | ((unsigned)f2bf(o[7] * inv) << 16);
      w1.x = (unsigned)f2bf(o[8] * inv)  | ((unsigned)f2bf(o[9] * inv) << 16);
      w1.y = (unsigned)f2bf(o[10] * inv) | ((unsigned)f2bf(o[11] * inv) << 16);
      w1.z = (unsigned)f2bf(o[12] * inv) | ((unsigned)f2bf(o[13] * inv) << 16);
      w1.w = (unsigned)f2bf(o[14] * inv) | ((unsigned)f2bf(o[15] * inv) << 16);
      *(uint4*)&sm.g.A16[lq][h * 16]     = w0;
      *(uint4*)&sm.g.A16[lq][h * 16 + 8] = w1;
    }
  }
  __syncthreads();
  // --- ao GEMM + residual ---
  {
    const u16* Bw = p.W + OFF_AO + l * 16384;
    const float* ab = p.ao_b + l * 128;
    const int cA = w * 32 + lr, cB = cA + 16;
    floatx4 a0 = FZ, a1 = FZ;
#pragma unroll
    for (int k0 = 0; k0 < 128; k0 += 32) {
      short8_t a  = *(const short8_t*)&sm.g.A16[lr & 7][k0 + quad * 8];
      short8_t b0 = *(const short8_t*)&Bw[(size_t)cA * 128 + k0 + quad * 8];
      short8_t b1 = *(const short8_t*)&Bw[(size_t)cB * 128 + k0 + quad * 8];
      a0 = __builtin_amdgcn_mfma_f32_16x16x32_bf16(a, b0, a0, 0, 0, 0);
      a1 = __builtin_amdgcn_mfma_f32_16x16x32_bf16(a, b1, a1, 0, 0, 0);
    }
    if (quad < 2) {
#pragma unroll
      for (int r = 0; r < 4; ++r) {
        Xs[quad * 4 + r][cA] += a0[r] + ab[cA];
        Xs[quad * 4 + r][cB] += a1[r] + ab[cB];
      }
    }
  }
  __syncthreads();
  // --- LN2 -> f1 (relu) -> FF1 ---
  stage_x(p.ln2_s + l * 128, p.ln2_b + l * 128, true);
  __syncthreads();
  {
    const u16* Bw = p.W + OFF_F1 + l * 32768;
    const float* fb = p.f1_b + l * 256;
    const int c0 = w * 64;
    floatx4 acc[4];
#pragma unroll
    for (int i = 0; i < 4; ++i) acc[i] = FZ;
#pragma unroll
    for (int k0 = 0; k0 < 128; k0 += 32) {
      short8_t a = *(const short8_t*)&sm.g.A16[lr & 7][k0 + quad * 8];
#pragma unroll
      for (int i = 0; i < 4; ++i) {
        short8_t b = *(const short8_t*)&Bw[(size_t)(c0 + i * 16 + lr) * 128 + k0 + quad * 8];
        acc[i] = __builtin_amdgcn_mfma_f32_16x16x32_bf16(a, b, acc[i], 0, 0, 0);
      }
    }
    if (quad < 2) {
#pragma unroll
      for (int i = 0; i < 4; ++i) {
        const int col = c0 + i * 16 + lr;
        const float bv = fb[col];
#pragma unroll
        for (int r = 0; r < 4; ++r)
          sm.g.FF1[quad * 4 + r][col] = f2bf(fmaxf(acc[i][r] + bv, 0.f));
      }
    }
  }
  __syncthreads();
  // --- f2 + residual ---
  {
    const u16* Bw = p.W + OFF_F2 + l * 32768;
    const float* fb = p.f2_b + l * 128;
    const int cA = w * 32 + lr, cB = cA + 16;
    floatx4 a0 = FZ, a1 = FZ;
#pragma unroll
    for (int k0 = 0; k0 < 256; k0 += 32) {
      short8_t a  = *(const short8_t*)&sm.g.FF1[lr & 7][k0 + quad * 8];
      short8_t b0 = *(const short8_t*)&Bw[(size_t)cA * 256 + k0 + quad * 8];
      short8_t b1 = *(const short8_t*)&Bw[(size_t)cB * 256 + k0 + quad * 8];
      a0 = __builtin_amdgcn_mfma_f32_16x16x32_bf16(a, b0, a0, 0, 0, 0);
      a1 = __builtin_amdgcn_mfma_f32_16x16x32_bf16(a, b1, a1, 0, 0, 0);
    }
    if (quad < 2) {
#pragma unroll
      for (int r = 0; r < 4; ++r) {
        Xs[quad * 4 + r][cA] += a0[r] + fb[cA];
        Xs[quad * 4 + r][cB] += a1[r] + fb[cB];
      }
    }
  }
  __syncthreads();
  if (l < 3) {
    // write X back, then LN1(l+1) + qkv(l+1)
    {
      const int r = t >> 5, j0 = (t & 31) * 4;
      *(float4*)&p.Xg[(size_t)(r0 + r) * H + j0] = *(const float4*)&Xs[r][j0];
    }
    stage_x(p.ln1_s + (l + 1) * 128, p.ln1_b + (l + 1) * 128, true);
    __syncthreads();
    {
      const u16* Bw = p.W + OFF_QKV + (l + 1) * 49152;
      const float* qb = p.qkv_b + (l + 1) * 384;
      const int c0 = w * 96;
      floatx4 acc[6];
#pragma unroll
      for (int i = 0; i < 6; ++i) acc[i] = FZ;
#pragma unroll
      for (int k0 = 0; k0 < 128; k0 += 32) {
        short8_t a = *(const short8_t*)&sm.g.A16[lr & 7][k0 + quad * 8];
#pragma unroll
        for (int i = 0; i < 6; ++i) {
          short8_t b = *(const short8_t*)&Bw[(size_t)(c0 + i * 16 + lr) * 128 + k0 + quad * 8];
          acc[i] = __builtin_amdgcn_mfma_f32_16x16x32_bf16(a, b, acc[i], 0, 0, 0);
        }
      }
      __syncthreads();
      if (quad < 2) {
#pragma unroll
        for (int i = 0; i < 6; ++i) {
          const int col = c0 + i * 16 + lr;
          const float bv = qb[col];
#pragma unroll
          for (int r = 0; r < 4; ++r)
            sm.QS[quad * 4 + r][col] = f2bf(acc[i][r] + bv);
        }
      }
      __syncthreads();
      u64* d64 = (u64*)(qdst + (size_t)r0 * 384);
      const u64* s64 = (const u64*)&sm.QS[0][0];
      for (int j = t; j < 768; j += BLK) d64[j] = s64[j]; // 8*384 u16 = 768 u64
    }
  } else {
    // --- heads: [lat1|b1] (N=192) -> lat2+normalize, beta ---
    stage_x(nullptr, nullptr, false);
    __syncthreads();
    {
      const u16* Bw = p.W + OFF_LAT1;
      const int c0 = w * 48;
      floatx4 acc[3];
#pragma unroll
      for (int i = 0; i < 3; ++i) acc[i] = FZ;
#pragma unroll
      for (int k0 = 0; k0 < 128; k0 += 32) {
        short8_t a = *(const short8_t*)&sm.g.A16[lr & 7][k0 + quad * 8];
#pragma unroll
        for (int i = 0; i < 3; ++i) {
          short8_t b = *(const short8_t*)&Bw[(size_t)(c0 + i * 16 + lr) * 128 + k0 + quad * 8];
          acc[i] = __builtin_amdgcn_mfma_f32_16x16x32_bf16(a, b, acc[i], 0, 0, 0);
        }
      }
      if (quad < 2) {
#pragma unroll
        for (int i = 0; i < 3; ++i) {
          const int col = c0 + i * 16 + lr;
          const float bv = col < 128 ? p.lat1_b[col] : p.b1_b[col - 128];
#pragma unroll
          for (int r = 0; r < 4; ++r)
            sm.g.FF1[quad * 4 + r][col] = f2bf(fmaxf(acc[i][r] + bv, 0.f));
        }
      }
    }
    __syncthreads();
    if (t < 128) {
      const int r = t >> 4, c = t & 15;
      float acc = p.lat2_b[c];
      const u16* gw = p.W + OFF_LAT2 + c * 128;
      for (int k = 0; k < 128; ++k) acc += bfu(sm.g.FF1[r][k]) * bfu(gw[k]);
      float ss = acc * acc;
      ss += __shfl_xor(ss, 1); ss += __shfl_xor(ss, 2);
      ss += __shfl_xor(ss, 4); ss += __shfl_xor(ss, 8);
      p.out[NT + (size_t)(r0 + r) * 16 + c] = acc / fmaxf(sqrtf(ss), 1e-12f);
      float v = 0.f;
#pragma unroll
      for (int i = 0; i < 4; ++i)
        v += bfu(sm.g.FF1[r][128 + c * 4 + i]) * p.b2_w[c * 4 + i];
      v += __shfl_xor(v, 1); v += __shfl_xor(v, 2);
      v += __shfl_xor(v, 4); v += __shfl_xor(v, 8);
      if (c == 0) {
        v += p.b2_b[0];
        const float beta = 1.f / (1.f + expf(-v));
        p.out[r0 + r] = fminf(fmaxf(beta, 1e-6f), 1.f - 1e-6f);
      }
    }
  }
}

extern "C" void kernel_launch(void* const* d_in, const int* in_sizes, int n_in,
                              void* d_out, int out_size, void* d_ws, size_t ws_size,
                              hipStream_t stream) {
  Prm prm;
  prm.xr    = (const float*)d_in[0];
  prm.in_w  = (const float*)d_in[2];  prm.in_b  = (const float*)d_in[3];
  prm.ln1_s = (const float*)d_in[4];  prm.ln1_b = (const float*)d_in[5];
  prm.qkv_w = (const float*)d_in[6];  prm.qkv_b = (const float*)d_in[7];
  prm.ao_w  = (const float*)d_in[8];  prm.ao_b  = (const float*)d_in[9];
  prm.ln2_s = (const float*)d_in[10]; prm.ln2_b = (const float*)d_in[11];
  prm.f1_w  = (const float*)d_in[12]; prm.f1_b  = (const float*)d_in[13];
  prm.f2_w  = (const float*)d_in[14]; prm.f2_b  = (const float*)d_in[15];
  prm.lat1_w= (const float*)d_in[16]; prm.lat1_b= (const float*)d_in[17];
  prm.lat2_w= (const float*)d_in[18]; prm.lat2_b= (const float*)d_in[19];
  prm.b1_w  = (const float*)d_in[20]; prm.b1_b  = (const float*)d_in[21];
  prm.b2_w  = (const float*)d_in[22]; prm.b2_b  = (const float*)d_in[23];
  prm.out   = (float*)d_out;

  char* pw = (char*)d_ws;
  prm.W    = (u16*)pw;   pw += ((size_t)W_TOTAL * 2 + 255) & ~(size_t)255;
  prm.QKV0 = (u16*)pw;   pw += (size_t)NT * 384 * 2;
  prm.QKV1 = (u16*)pw;   pw += (size_t)NT * 384 * 2;
  prm.Xg   = (float*)pw; pw += (size_t)NT * H * 4;
  prm.NI   = (int*)pw;   pw += (size_t)NT * CAP * 4;
  prm.NC   = (int*)pw;   pw += (size_t)NT * 4;

  prep_kernel<<<GRID, BLK, 0, stream>>>(prm);
  layer_kernel<<<GRID, BLK, 0, stream>>>(prm, 0, prm.QKV0, prm.QKV1);
  layer_kernel<<<GRID, BLK, 0, stream>>>(prm, 1, prm.QKV1, prm.QKV0);
  layer_kernel<<<GRID, BLK, 0, stream>>>(prm, 2, prm.QKV0, prm.QKV1);
  layer_kernel<<<GRID, BLK, 0, stream>>>(prm, 3, prm.QKV1, nullptr);
}

// Round 12
// 201.748 us; speedup vs baseline: 1.1442x; 1.1442x over previous
//
#include <hip/hip_runtime.h>
#include <hip/hip_bf16.h>

typedef unsigned short u16;
typedef unsigned long long u64;
typedef short short8_t __attribute__((ext_vector_type(8)));
typedef float floatx4 __attribute__((ext_vector_type(4)));

constexpr int NT = 4096, H = 128, CAP = 64;
constexpr int GRID = 256, BLK = 1024, GSTRIDE = GRID * BLK;
constexpr int ROWS = 16;                    // rows per block; 16 waves/CU

// bf16 weight arena element offsets (layer-0 qkv region unused: prep reads f32)
constexpr int OFF_QKV  = 0;                 // 4*384*128
constexpr int OFF_AO   = 196608;            // 4*128*128
constexpr int OFF_F1   = 262144;            // 4*256*128
constexpr int OFF_F2   = 393216;            // 4*128*256
constexpr int OFF_LAT1 = 524288;            // 128*128
constexpr int OFF_B1   = 540672;            // 64*128
constexpr int OFF_LAT2 = 548864;            // 16*128
constexpr int W_TOTAL  = 550912;

__device__ __forceinline__ float bfu(u16 u) { return __uint_as_float(((unsigned)u) << 16); }
__device__ __forceinline__ u16 f2bf(float f) {
  unsigned u = __float_as_uint(f);
  u += 0x7fffu + ((u >> 16) & 1u);          // RNE
  return (u16)(u >> 16);
}
__device__ __forceinline__ void unpack8(uint4 u, float* f) {
  f[0] = __uint_as_float(u.x << 16); f[1] = __uint_as_float(u.x & 0xffff0000u);
  f[2] = __uint_as_float(u.y << 16); f[3] = __uint_as_float(u.y & 0xffff0000u);
  f[4] = __uint_as_float(u.z << 16); f[5] = __uint_as_float(u.z & 0xffff0000u);
  f[6] = __uint_as_float(u.w << 16); f[7] = __uint_as_float(u.w & 0xffff0000u);
}
__device__ __forceinline__ short8_t cvt8(const float* bp) {   // f32 row -> bf16 frag
  const float4 f0 = *(const float4*)bp, f1 = *(const float4*)(bp + 4);
  short8_t r;
  r[0] = (short)f2bf(f0.x); r[1] = (short)f2bf(f0.y);
  r[2] = (short)f2bf(f0.z); r[3] = (short)f2bf(f0.w);
  r[4] = (short)f2bf(f1.x); r[5] = (short)f2bf(f1.y);
  r[6] = (short)f2bf(f1.z); r[7] = (short)f2bf(f1.w);
  return r;
}

struct Prm {
  const float *xr, *in_w, *in_b, *ln1_s, *ln1_b, *qkv_w, *qkv_b, *ao_w, *ao_b,
              *ln2_s, *ln2_b, *f1_w, *f1_b, *f2_w, *f2_b, *lat1_w, *lat1_b,
              *lat2_w, *lat2_b, *b1_w, *b1_b, *b2_w, *b2_b;
  u16* W; u16* QKV0; u16* QKV1; float* Xg; int* NI; int* NC; float* out;
};

// ======================= K0: prep + qkv layer 0 =======================
__global__ __launch_bounds__(BLK, 1) void prep_kernel(Prm p) {
  const int t = threadIdx.x, bid = blockIdx.x;
  const int lane = t & 63, w = t >> 6;          // 16 waves
  const int lr = lane & 15, quad = lane >> 4;
  const int gtid = bid * BLK + t;
  const int r0 = bid * ROWS;
  const floatx4 FZ = {0.f, 0.f, 0.f, 0.f};

  __shared__ float Xs[ROWS][132];
  __shared__ union {
    unsigned long long words[8][64];
    struct { u16 A16[ROWS][152]; } g;
    u16 QS[ROWS][384];
  } sm;

  // wconv (skip unused layer-0 qkv region)
  for (int i = 49152 + gtid; i < W_TOTAL; i += GSTRIDE) {
    float v;
    if      (i < OFF_AO)   v = p.qkv_w[i];
    else if (i < OFF_F1)   v = p.ao_w[i - OFF_AO];
    else if (i < OFF_F2)   v = p.f1_w[i - OFF_F1];
    else if (i < OFF_LAT1) v = p.f2_w[i - OFF_F2];
    else if (i < OFF_B1)   v = p.lat1_w[i - OFF_LAT1];
    else if (i < OFF_LAT2) v = p.b1_w[i - OFF_B1];
    else                   v = p.lat2_w[i - OFF_LAT2];
    p.W[i] = f2bf(v);
  }
  // in_proj for own 16 rows -> Xs + Xg
  for (int i = t; i < ROWS * H; i += BLK) {
    const int r = i >> 7, c = i & 127;
    const float* xp = p.xr + (size_t)(r0 + r) * 16;
    const float* wp = p.in_w + c * 16;
    float acc = p.in_b[c];
#pragma unroll
    for (int k = 0; k < 16; ++k) acc += xp[k] * wp[k];
    Xs[r][c] = acc;
    p.Xg[(size_t)(r0 + r) * H + c] = acc;
  }
  // neighbor lists for own 16 rows -> global NI/NC (two passes of 8 rows)
  for (int uu = 0; uu < 2; ++uu) {
    const int q0 = r0 + uu * 8;
    double qe[8], qp_[8];
#pragma unroll
    for (int j = 0; j < 8; ++j) {
      qe[j]  = (double)p.xr[(q0 + j) * 16 + 1] * 5.24 - 2.62;
      qp_[j] = (double)p.xr[(q0 + j) * 16 + 2] * 6.2832 - 3.1416;
    }
    for (int c = 0; c < 4; ++c) {               // 4 chunks of 1024 keys
      const int k = c * 1024 + t;
      const double ke = (double)p.xr[k * 16 + 1] * 5.24 - 2.62;
      const double kp = (double)p.xr[k * 16 + 2] * 6.2832 - 3.1416;
#pragma unroll
      for (int j = 0; j < 8; ++j) {
        const double de = qe[j] - ke;
        double dp = qp_[j] - kp;
        dp -= 6.283185307179586 * rint(dp * 0.15915494309189535);  // atan2 wrap
        const unsigned long long bm = __ballot((de * de + dp * dp) <= 0.04);
        if (lane == 0) sm.words[j][c * 16 + w] = bm;  // word i covers keys [i*64,+64)
      }
    }
    __syncthreads();
    if (w < 8) {                                // wave w compacts row q0+w
      unsigned long long m = sm.words[w][lane];
      const int cnt = __popcll(m);
      int incl = cnt;
#pragma unroll
      for (int off = 1; off < 64; off <<= 1) {
        const int n = __shfl_up(incl, off);
        if (lane >= off) incl += n;
      }
      int pos = incl - cnt;
      const int qq = q0 + w;
      const int kbase = lane * 64;
      while (m) {
        const int b = __builtin_ctzll(m);
        m &= m - 1;
        if (pos < CAP) p.NI[qq * CAP + pos] = kbase + b;
        ++pos;
      }
      if (lane == 63) p.NC[qq] = incl > CAP ? CAP : incl;
    }
    __syncthreads();
  }
  // LN1(0) -> A16, one wave per row
  {
    const int r = w, j0 = lane * 2;
    float v0 = Xs[r][j0], v1 = Xs[r][j0 + 1];
    float s = v0 + v1, ss = v0 * v0 + v1 * v1;
#pragma unroll
    for (int off = 1; off <= 32; off <<= 1) {
      s += __shfl_xor(s, off); ss += __shfl_xor(ss, off);
    }
    const float mean = s * (1.f / 128.f);
    const float rstd = rsqrtf(ss * (1.f / 128.f) - mean * mean + 1e-5f);
    v0 = (v0 - mean) * rstd * p.ln1_s[j0]     + p.ln1_b[j0];
    v1 = (v1 - mean) * rstd * p.ln1_s[j0 + 1] + p.ln1_b[j0 + 1];
    *(unsigned*)&sm.g.A16[r][j0] = (unsigned)f2bf(v0) | ((unsigned)f2bf(v1) << 16);
  }
  __syncthreads();
  // qkv0 from f32 weights (register-convert); 24 tiles: w<8 -> 2, w>=8 -> 1
  {
    floatx4 a0 = FZ, a1 = FZ;
    const int cA = (w < 8) ? (w * 32 + lr) : (256 + (w - 8) * 16 + lr);
    const int cB = cA + 16;                     // only used when w<8
#pragma unroll
    for (int k0 = 0; k0 < 128; k0 += 32) {
      short8_t a  = *(const short8_t*)&sm.g.A16[lr][k0 + quad * 8];
      short8_t b0 = cvt8(&p.qkv_w[(size_t)cA * 128 + k0 + quad * 8]);
      a0 = __builtin_amdgcn_mfma_f32_16x16x32_bf16(a, b0, a0, 0, 0, 0);
      if (w < 8) {
        short8_t b1 = cvt8(&p.qkv_w[(size_t)cB * 128 + k0 + quad * 8]);
        a1 = __builtin_amdgcn_mfma_f32_16x16x32_bf16(a, b1, a1, 0, 0, 0);
      }
    }
    __syncthreads();
#pragma unroll
    for (int r = 0; r < 4; ++r) {
      const int row = quad * 4 + r;
      sm.QS[row][cA] = f2bf(a0[r] + p.qkv_b[cA]);
      if (w < 8) sm.QS[row][cB] = f2bf(a1[r] + p.qkv_b[cB]);
    }
    __syncthreads();
    u64* d64 = (u64*)(p.QKV0 + (size_t)r0 * 384);
    const u64* s64 = (const u64*)&sm.QS[0][0];
    for (int j = t; j < 1536; j += BLK) d64[j] = s64[j];  // 16 rows*384 u16
  }
}

// ============ K1..K4: one transformer layer (+qkv next / heads) ============
__global__ __launch_bounds__(BLK, 1) void layer_kernel(Prm p, int l,
                                                       const u16* __restrict__ qsrc,
                                                       u16* __restrict__ qdst) {
  const int t = threadIdx.x, bid = blockIdx.x;
  const int lane = t & 63, w = t >> 6;          // 16 waves
  const int lr = lane & 15, quad = lane >> 4;
  const int r0 = bid * ROWS;
  const floatx4 FZ = {0.f, 0.f, 0.f, 0.f};

  __shared__ float Xs[ROWS][132];
  __shared__ int NIs[ROWS][CAP];
  __shared__ int NCs[ROWS];
  __shared__ union {
    struct { u16 A16[ROWS][152]; u16 FF1[ROWS][280]; } g;
    u16 QS[ROWS][384];
  } sm;

  // load block state: one wave per X row; NIs in one stride
  {
    const int r = w, j0 = lane * 2;
    *(float2*)&Xs[r][j0] = *(const float2*)&p.Xg[(size_t)(r0 + r) * H + j0];
    if (t < ROWS * CAP) (&NIs[0][0])[t] = p.NI[r0 * CAP + t];
    if (t < ROWS) NCs[t] = p.NC[r0 + t];
  }

  auto stage_x = [&](const float* sc, const float* bi, bool do_ln) {
    const int r = w, j0 = lane * 2;
    float v0 = Xs[r][j0], v1 = Xs[r][j0 + 1];
    if (do_ln) {
      float s = v0 + v1, ss = v0 * v0 + v1 * v1;
#pragma unroll
      for (int off = 1; off <= 32; off <<= 1) {
        s += __shfl_xor(s, off); ss += __shfl_xor(ss, off);
      }
      const float mean = s * (1.f / 128.f);
      const float rstd = rsqrtf(ss * (1.f / 128.f) - mean * mean + 1e-5f);
      v0 = (v0 - mean) * rstd * sc[j0]     + bi[j0];
      v1 = (v1 - mean) * rstd * sc[j0 + 1] + bi[j0 + 1];
    }
    *(unsigned*)&sm.g.A16[r][j0] = (unsigned)f2bf(v0) | ((unsigned)f2bf(v1) << 16);
  };
  __syncthreads();

  // --- attention: 128 (q,h) pairs, 8 threads/pair over neighbors ---
  {
    const int pr = t >> 3, sub = t & 7;
    const int lq = pr >> 3, h = pr & 7;
    const u16* qp = qsrc + (size_t)(r0 + lq) * 384 + h * 16;
    float qv[16];
    { uint4 a = *(const uint4*)qp, b = *(const uint4*)(qp + 8);
      unpack8(a, qv); unpack8(b, qv + 8); }
#pragma unroll
    for (int d = 0; d < 16; ++d) qv[d] *= 0.25f;        // 1/sqrt(HD)
    float o[16];
#pragma unroll
    for (int d = 0; d < 16; ++d) o[d] = 0.f;
    float se = 0.f;
    const int cnt = NCs[lq];
    for (int i = sub; i < cnt; i += 8) {
      const int nb = NIs[lq][i];
      const u16* kp = qsrc + (size_t)nb * 384 + 128 + h * 16;
      float kv[16], vv[16];
      { uint4 a = *(const uint4*)kp;         uint4 b = *(const uint4*)(kp + 8);
        unpack8(a, kv); unpack8(b, kv + 8); }
      { uint4 a = *(const uint4*)(kp + 128); uint4 b = *(const uint4*)(kp + 136);
        unpack8(a, vv); unpack8(b, vv + 8); }
      float s0 = 0.f, s1 = 0.f, s2 = 0.f, s3 = 0.f;
#pragma unroll
      for (int d = 0; d < 16; d += 4) {
        s0 += qv[d] * kv[d];         s1 += qv[d + 1] * kv[d + 1];
        s2 += qv[d + 2] * kv[d + 2]; s3 += qv[d + 3] * kv[d + 3];
      }
      const float e = expf((s0 + s1) + (s2 + s3));      // |s|<~0.5, no max-sub
      se += e;
#pragma unroll
      for (int d = 0; d < 16; ++d) o[d] += e * vv[d];
    }
#pragma unroll
    for (int off = 1; off <= 4; off <<= 1) {
#pragma unroll
      for (int d = 0; d < 16; ++d) o[d] += __shfl_xor(o[d], off);
      se += __shfl_xor(se, off);
    }
    if (sub == 0) {
      const float inv = 1.f / se;
      uint4 w0, w1;
      w0.x = (unsigned)f2bf(o[0] * inv)  | ((unsigned)f2bf(o[1] * inv) << 16);
      w0.y = (unsigned)f2bf(o[2] * inv)  | ((unsigned)f2bf(o[3] * inv) << 16);
      w0.z = (unsigned)f2bf(o[4] * inv)  | ((unsigned)f2bf(o[5] * inv) << 16);
      w0.w = (unsigned)f2bf(o[6] * inv)  | ((unsigned)f2bf(o[7] * inv) << 16);
      w1.x = (unsigned)f2bf(o[8] * inv)  | ((unsigned)f2bf(o[9] * inv) << 16);
      w1.y = (unsigned)f2bf(o[10] * inv) | ((unsigned)f2bf(o[11] * inv) << 16);
      w1.z = (unsigned)f2bf(o[12] * inv) | ((unsigned)f2bf(o[13] * inv) << 16);
      w1.w = (unsigned)f2bf(o[14] * inv) | ((unsigned)f2bf(o[15] * inv) << 16);
      *(uint4*)&sm.g.A16[lq][h * 16]     = w0;
      *(uint4*)&sm.g.A16[lq][h * 16 + 8] = w1;
    }
  }
  __syncthreads();
  // --- ao GEMM + residual (waves 0-7) ---
  if (w < 8) {
    const u16* Bw = p.W + OFF_AO + l * 16384;
    const float* ab = p.ao_b + l * 128;
    const int col = w * 16 + lr;
    floatx4 acc = FZ;
#pragma unroll
    for (int k0 = 0; k0 < 128; k0 += 32) {
      short8_t a = *(const short8_t*)&sm.g.A16[lr][k0 + quad * 8];
      short8_t b = *(const short8_t*)&Bw[(size_t)col * 128 + k0 + quad * 8];
      acc = __builtin_amdgcn_mfma_f32_16x16x32_bf16(a, b, acc, 0, 0, 0);
    }
    const float bv = ab[col];
#pragma unroll
    for (int r = 0; r < 4; ++r)
      Xs[quad * 4 + r][col] += acc[r] + bv;
  }
  __syncthreads();
  // --- LN2 -> f1 (relu) -> FF1 (16 waves, 1 tile each) ---
  stage_x(p.ln2_s + l * 128, p.ln2_b + l * 128, true);
  __syncthreads();
  {
    const u16* Bw = p.W + OFF_F1 + l * 32768;
    const float* fb = p.f1_b + l * 256;
    const int col = w * 16 + lr;
    floatx4 acc = FZ;
#pragma unroll
    for (int k0 = 0; k0 < 128; k0 += 32) {
      short8_t a = *(const short8_t*)&sm.g.A16[lr][k0 + quad * 8];
      short8_t b = *(const short8_t*)&Bw[(size_t)col * 128 + k0 + quad * 8];
      acc = __builtin_amdgcn_mfma_f32_16x16x32_bf16(a, b, acc, 0, 0, 0);
    }
    const float bv = fb[col];
#pragma unroll
    for (int r = 0; r < 4; ++r)
      sm.g.FF1[quad * 4 + r][col] = f2bf(fmaxf(acc[r] + bv, 0.f));
  }
  __syncthreads();
  // --- f2 + residual (waves 0-7) ---
  if (w < 8) {
    const u16* Bw = p.W + OFF_F2 + l * 32768;
    const float* fb = p.f2_b + l * 128;
    const int col = w * 16 + lr;
    floatx4 acc = FZ;
#pragma unroll
    for (int k0 = 0; k0 < 256; k0 += 32) {
      short8_t a = *(const short8_t*)&sm.g.FF1[lr][k0 + quad * 8];
      short8_t b = *(const short8_t*)&Bw[(size_t)col * 256 + k0 + quad * 8];
      acc = __builtin_amdgcn_mfma_f32_16x16x32_bf16(a, b, acc, 0, 0, 0);
    }
    const float bv = fb[col];
#pragma unroll
    for (int r = 0; r < 4; ++r)
      Xs[quad * 4 + r][col] += acc[r] + bv;
  }
  __syncthreads();
  if (l < 3) {
    // write X back (one wave per row), then LN1(l+1) + qkv(l+1)
    {
      const int r = w, j0 = lane * 2;
      *(float2*)&p.Xg[(size_t)(r0 + r) * H + j0] = *(const float2*)&Xs[r][j0];
    }
    stage_x(p.ln1_s + (l + 1) * 128, p.ln1_b + (l + 1) * 128, true);
    __syncthreads();
    {
      const u16* Bw = p.W + OFF_QKV + (l + 1) * 49152;
      const float* qb = p.qkv_b + (l + 1) * 384;
      floatx4 a0 = FZ, a1 = FZ;
      const int cA = (w < 8) ? (w * 32 + lr) : (256 + (w - 8) * 16 + lr);
      const int cB = cA + 16;                   // only used when w<8
#pragma unroll
      for (int k0 = 0; k0 < 128; k0 += 32) {
        short8_t a  = *(const short8_t*)&sm.g.A16[lr][k0 + quad * 8];
        short8_t b0 = *(const short8_t*)&Bw[(size_t)cA * 128 + k0 + quad * 8];
        a0 = __builtin_amdgcn_mfma_f32_16x16x32_bf16(a, b0, a0, 0, 0, 0);
        if (w < 8) {
          short8_t b1 = *(const short8_t*)&Bw[(size_t)cB * 128 + k0 + quad * 8];
          a1 = __builtin_amdgcn_mfma_f32_16x16x32_bf16(a, b1, a1, 0, 0, 0);
        }
      }
      __syncthreads();
#pragma unroll
      for (int r = 0; r < 4; ++r) {
        const int row = quad * 4 + r;
        sm.QS[row][cA] = f2bf(a0[r] + qb[cA]);
        if (w < 8) sm.QS[row][cB] = f2bf(a1[r] + qb[cB]);
      }
      __syncthreads();
      u64* d64 = (u64*)(qdst + (size_t)r0 * 384);
      const u64* s64 = (const u64*)&sm.QS[0][0];
      for (int j = t; j < 1536; j += BLK) d64[j] = s64[j];
    }
  } else {
    // --- heads: [lat1|b1] (N=192, 12 tiles over waves 0-11) ---
    stage_x(nullptr, nullptr, false);
    __syncthreads();
    if (w < 12) {
      const u16* Bw = p.W + OFF_LAT1;
      const int col = w * 16 + lr;
      floatx4 acc = FZ;
#pragma unroll
      for (int k0 = 0; k0 < 128; k0 += 32) {
        short8_t a = *(const short8_t*)&sm.g.A16[lr][k0 + quad * 8];
        short8_t b = *(const short8_t*)&Bw[(size_t)col * 128 + k0 + quad * 8];
        acc = __builtin_amdgcn_mfma_f32_16x16x32_bf16(a, b, acc, 0, 0, 0);
      }
      const float bv = col < 128 ? p.lat1_b[col] : p.b1_b[col - 128];
#pragma unroll
      for (int r = 0; r < 4; ++r)
        sm.g.FF1[quad * 4 + r][col] = f2bf(fmaxf(acc[r] + bv, 0.f));
    }
    __syncthreads();
    if (t < 256) {
      const int r = t >> 4, c = t & 15;
      float acc = p.lat2_b[c];
      const u16* gw = p.W + OFF_LAT2 + c * 128;
      for (int k = 0; k < 128; ++k) acc += bfu(sm.g.FF1[r][k]) * bfu(gw[k]);
      float ss = acc * acc;
      ss += __shfl_xor(ss, 1); ss += __shfl_xor(ss, 2);
      ss += __shfl_xor(ss, 4); ss += __shfl_xor(ss, 8);
      p.out[NT + (size_t)(r0 + r) * 16 + c] = acc / fmaxf(sqrtf(ss), 1e-12f);
      float v = 0.f;
#pragma unroll
      for (int i = 0; i < 4; ++i)
        v += bfu(sm.g.FF1[r][128 + c * 4 + i]) * p.b2_w[c * 4 + i];
      v += __shfl_xor(v, 1); v += __shfl_xor(v, 2);
      v += __shfl_xor(v, 4); v += __shfl_xor(v, 8);
      if (c == 0) {
        v += p.b2_b[0];
        const float beta = 1.f / (1.f + expf(-v));
        p.out[r0 + r] = fminf(fmaxf(beta, 1e-6f), 1.f - 1e-6f);
      }
    }
  }
}

extern "C" void kernel_launch(void* const* d_in, const int* in_sizes, int n_in,
                              void* d_out, int out_size, void* d_ws, size_t ws_size,
                              hipStream_t stream) {
  Prm prm;
  prm.xr    = (const float*)d_in[0];
  prm.in_w  = (const float*)d_in[2];  prm.in_b  = (const float*)d_in[3];
  prm.ln1_s = (const float*)d_in[4];  prm.ln1_b = (const float*)d_in[5];
  prm.qkv_w = (const float*)d_in[6];  prm.qkv_b = (const float*)d_in[7];
  prm.ao_w  = (const float*)d_in[8];  prm.ao_b  = (const float*)d_in[9];
  prm.ln2_s = (const float*)d_in[10]; prm.ln2_b = (const float*)d_in[11];
  prm.f1_w  = (const float*)d_in[12]; prm.f1_b  = (const float*)d_in[13];
  prm.f2_w  = (const float*)d_in[14]; prm.f2_b  = (const float*)d_in[15];
  prm.lat1_w= (const float*)d_in[16]; prm.lat1_b= (const float*)d_in[17];
  prm.lat2_w= (const float*)d_in[18]; prm.lat2_b= (const float*)d_in[19];
  prm.b1_w  = (const float*)d_in[20]; prm.b1_b  = (const float*)d_in[21];
  prm.b2_w  = (const float*)d_in[22]; prm.b2_b  = (const float*)d_in[23];
  prm.out   = (float*)d_out;

  char* pw = (char*)d_ws;
  prm.W    = (u16*)pw;   pw += ((size_t)W_TOTAL * 2 + 255) & ~(size_t)255;
  prm.QKV0 = (u16*)pw;   pw += (size_t)NT * 384 * 2;
  prm.QKV1 = (u16*)pw;   pw += (size_t)NT * 384 * 2;
  prm.Xg   = (float*)pw; pw += (size_t)NT * H * 4;
  prm.NI   = (int*)pw;   pw += (size_t)NT * CAP * 4;
  prm.NC   = (int*)pw;   pw += (size_t)NT * 4;

  prep_kernel<<<GRID, BLK, 0, stream>>>(prm);
  layer_kernel<<<GRID, BLK, 0, stream>>>(prm, 0, prm.QKV0, prm.QKV1);
  layer_kernel<<<GRID, BLK, 0, stream>>>(prm, 1, prm.QKV1, prm.QKV0);
  layer_kernel<<<GRID, BLK, 0, stream>>>(prm, 2, prm.QKV0, prm.QKV1);
  layer_kernel<<<GRID, BLK, 0, stream>>>(prm, 3, prm.QKV1, nullptr);
}

// Round 13
// 198.248 us; speedup vs baseline: 1.1644x; 1.0177x over previous
//
#include <hip/hip_runtime.h>
#include <hip/hip_bf16.h>

typedef unsigned short u16;
typedef short short8_t __attribute__((ext_vector_type(8)));
typedef float floatx4 __attribute__((ext_vector_type(4)));

constexpr int NT = 4096, H = 128, CAP = 64;
constexpr int GRID = 256, BLK = 512, GSTRIDE = GRID * BLK;

// bf16 weight arena element offsets (layer-0 qkv region unused: prep reads f32)
constexpr int OFF_QKV  = 0;                 // 4*384*128
constexpr int OFF_AO   = 196608;            // 4*128*128
constexpr int OFF_F1   = 262144;            // 4*256*128
constexpr int OFF_F2   = 393216;            // 4*128*256
constexpr int OFF_LAT1 = 524288;            // 128*128
constexpr int OFF_B1   = 540672;            // 64*128
constexpr int OFF_LAT2 = 548864;            // 16*128
constexpr int W_TOTAL  = 550912;

__device__ __forceinline__ float bfu(u16 u) { return __uint_as_float(((unsigned)u) << 16); }
__device__ __forceinline__ u16 f2bf(float f) {
  unsigned u = __float_as_uint(f);
  u += 0x7fffu + ((u >> 16) & 1u);          // RNE
  return (u16)(u >> 16);
}
__device__ __forceinline__ void unpack8(uint4 u, float* f) {
  f[0] = __uint_as_float(u.x << 16); f[1] = __uint_as_float(u.x & 0xffff0000u);
  f[2] = __uint_as_float(u.y << 16); f[3] = __uint_as_float(u.y & 0xffff0000u);
  f[4] = __uint_as_float(u.z << 16); f[5] = __uint_as_float(u.z & 0xffff0000u);
  f[6] = __uint_as_float(u.w << 16); f[7] = __uint_as_float(u.w & 0xffff0000u);
}
__device__ __forceinline__ short8_t cvt8(const float* bp) {   // f32 row -> bf16 frag
  const float4 f0 = *(const float4*)bp, f1 = *(const float4*)(bp + 4);
  short8_t r;
  r[0] = (short)f2bf(f0.x); r[1] = (short)f2bf(f0.y);
  r[2] = (short)f2bf(f0.z); r[3] = (short)f2bf(f0.w);
  r[4] = (short)f2bf(f1.x); r[5] = (short)f2bf(f1.y);
  r[6] = (short)f2bf(f1.z); r[7] = (short)f2bf(f1.w);
  return r;
}

struct Prm {
  const float *xr, *in_w, *in_b, *ln1_s, *ln1_b, *qkv_w, *qkv_b, *ao_w, *ao_b,
              *ln2_s, *ln2_b, *f1_w, *f1_b, *f2_w, *f2_b, *lat1_w, *lat1_b,
              *lat2_w, *lat2_b, *b1_w, *b1_b, *b2_w, *b2_b;
  u16* W; u16* QKV0; u16* QKV1; float* Xg; int* NI; int* NC; float* out;
};

// ======================= K0: prep + qkv layer 0 =======================
// wconv (layers 1-3 + tails), in_proj -> Xs/Xg, neighbor lists -> NI/NC,
// LN1(0) + qkv0 (f32 weights, register-convert) -> QKV0.
__global__ __launch_bounds__(BLK, 2) void prep_kernel(Prm p) {
  const int t = threadIdx.x, bid = blockIdx.x;
  const int lane = t & 63, w = t >> 6;
  const int lr = lane & 15, quad = lane >> 4;
  const int gtid = bid * BLK + t;
  const int r0 = bid * 16;
  const floatx4 FZ = {0.f, 0.f, 0.f, 0.f};

  __shared__ float Xs[16][132];
  __shared__ union {
    unsigned long long words[8][64];
    struct { u16 A16[16][152]; } g;
    u16 QS[16][384];
  } sm;

  // wconv: skip unused layer-0 qkv region
  for (int i = 49152 + gtid; i < W_TOTAL; i += GSTRIDE) {
    float v;
    if      (i < OFF_AO)   v = p.qkv_w[i];
    else if (i < OFF_F1)   v = p.ao_w[i - OFF_AO];
    else if (i < OFF_F2)   v = p.f1_w[i - OFF_F1];
    else if (i < OFF_LAT1) v = p.f2_w[i - OFF_F2];
    else if (i < OFF_B1)   v = p.lat1_w[i - OFF_LAT1];
    else if (i < OFF_LAT2) v = p.b1_w[i - OFF_B1];
    else                   v = p.lat2_w[i - OFF_LAT2];
    p.W[i] = f2bf(v);
  }
  // in_proj for own 16 rows -> Xs + Xg
  for (int i = t; i < 16 * H; i += BLK) {
    const int r = i >> 7, c = i & 127;
    const float* xp = p.xr + (size_t)(r0 + r) * 16;
    const float* wp = p.in_w + c * 16;
    float acc = p.in_b[c];
#pragma unroll
    for (int k = 0; k < 16; ++k) acc += xp[k] * wp[k];
    Xs[r][c] = acc;
    p.Xg[(size_t)(r0 + r) * H + c] = acc;
  }
  // neighbor lists for own 16 rows -> global NI/NC
  for (int uu = 0; uu < 2; ++uu) {
    const int q0 = r0 + uu * 8;
    double qe[8], qp_[8];
#pragma unroll
    for (int j = 0; j < 8; ++j) {
      qe[j]  = (double)p.xr[(q0 + j) * 16 + 1] * 5.24 - 2.62;
      qp_[j] = (double)p.xr[(q0 + j) * 16 + 2] * 6.2832 - 3.1416;
    }
    for (int c = 0; c < 8; ++c) {
      const int k = c * 512 + t;
      const double ke = (double)p.xr[k * 16 + 1] * 5.24 - 2.62;
      const double kp = (double)p.xr[k * 16 + 2] * 6.2832 - 3.1416;
#pragma unroll
      for (int j = 0; j < 8; ++j) {
        const double de = qe[j] - ke;
        double dp = qp_[j] - kp;
        dp -= 6.283185307179586 * rint(dp * 0.15915494309189535);  // atan2 wrap
        const unsigned long long bm = __ballot((de * de + dp * dp) <= 0.04);
        if (lane == 0) sm.words[j][c * 8 + w] = bm;
      }
    }
    __syncthreads();
    {
      unsigned long long m = sm.words[w][lane];
      const int cnt = __popcll(m);
      int incl = cnt;
#pragma unroll
      for (int off = 1; off < 64; off <<= 1) {
        const int n = __shfl_up(incl, off);
        if (lane >= off) incl += n;
      }
      int pos = incl - cnt;
      const int qq = q0 + w;
      const int kbase = (lane >> 3) * 512 + (lane & 7) * 64;
      while (m) {
        const int b = __builtin_ctzll(m);
        m &= m - 1;
        if (pos < CAP) p.NI[qq * CAP + pos] = kbase + b;
        ++pos;
      }
      if (lane == 63) p.NC[qq] = incl > CAP ? CAP : incl;
    }
    __syncthreads();
  }
  // LN1(0) -> A16
  {
    const int r = t >> 5, j0 = (t & 31) * 4;
    const float4 xv = *(const float4*)&Xs[r][j0];
    float v0 = xv.x, v1 = xv.y, v2 = xv.z, v3 = xv.w;
    float s = v0 + v1 + v2 + v3;
    float ss = v0 * v0 + v1 * v1 + v2 * v2 + v3 * v3;
#pragma unroll
    for (int off = 1; off <= 16; off <<= 1) {
      s += __shfl_xor(s, off); ss += __shfl_xor(ss, off);
    }
    const float mean = s * (1.f / 128.f);
    const float rstd = rsqrtf(ss * (1.f / 128.f) - mean * mean + 1e-5f);
    v0 = (v0 - mean) * rstd * p.ln1_s[j0]     + p.ln1_b[j0];
    v1 = (v1 - mean) * rstd * p.ln1_s[j0 + 1] + p.ln1_b[j0 + 1];
    v2 = (v2 - mean) * rstd * p.ln1_s[j0 + 2] + p.ln1_b[j0 + 2];
    v3 = (v3 - mean) * rstd * p.ln1_s[j0 + 3] + p.ln1_b[j0 + 3];
    uint2 pk;
    pk.x = (unsigned)f2bf(v0) | ((unsigned)f2bf(v1) << 16);
    pk.y = (unsigned)f2bf(v2) | ((unsigned)f2bf(v3) << 16);
    *(uint2*)&sm.g.A16[r][j0] = pk;
  }
  __syncthreads();
  // qkv0 from f32 weights
  {
    const int c0 = w * 48;
    floatx4 a0 = FZ, a1 = FZ, a2 = FZ;
#pragma unroll
    for (int k0 = 0; k0 < 128; k0 += 32) {
      short8_t a  = *(const short8_t*)&sm.g.A16[lr][k0 + quad * 8];
      short8_t b0 = cvt8(&p.qkv_w[(size_t)(c0 + lr) * 128 + k0 + quad * 8]);
      short8_t b1 = cvt8(&p.qkv_w[(size_t)(c0 + 16 + lr) * 128 + k0 + quad * 8]);
      short8_t b2 = cvt8(&p.qkv_w[(size_t)(c0 + 32 + lr) * 128 + k0 + quad * 8]);
      a0 = __builtin_amdgcn_mfma_f32_16x16x32_bf16(a, b0, a0, 0, 0, 0);
      a1 = __builtin_amdgcn_mfma_f32_16x16x32_bf16(a, b1, a1, 0, 0, 0);
      a2 = __builtin_amdgcn_mfma_f32_16x16x32_bf16(a, b2, a2, 0, 0, 0);
    }
    __syncthreads();
#pragma unroll
    for (int r = 0; r < 4; ++r) {
      const int row = quad * 4 + r;
      sm.QS[row][c0 + lr]      = f2bf(a0[r] + p.qkv_b[c0 + lr]);
      sm.QS[row][c0 + 16 + lr] = f2bf(a1[r] + p.qkv_b[c0 + 16 + lr]);
      sm.QS[row][c0 + 32 + lr] = f2bf(a2[r] + p.qkv_b[c0 + 32 + lr]);
    }
    __syncthreads();
    unsigned long long* d64 = (unsigned long long*)(p.QKV0 + (size_t)r0 * 384);
    const unsigned long long* s64 = (const unsigned long long*)&sm.QS[0][0];
    for (int j = t; j < 1536; j += BLK) d64[j] = s64[j];
  }
}

// ================= K1..K4: one transformer layer (+qkv next / heads) =================
__global__ __launch_bounds__(BLK, 2) void layer_kernel(Prm p, int l,
                                                       const u16* __restrict__ qsrc,
                                                       u16* __restrict__ qdst) {
  const int t = threadIdx.x, bid = blockIdx.x;
  const int lane = t & 63, w = t >> 6;
  const int lr = lane & 15, quad = lane >> 4;
  const int r0 = bid * 16;
  const floatx4 FZ = {0.f, 0.f, 0.f, 0.f};

  __shared__ float Xs[16][132];
  __shared__ int NIs[16][CAP];
  __shared__ int NCs[16];
  __shared__ union {
    struct { u16 A16[16][152]; u16 FF1[16][280]; } g;
    u16 QS[16][384];
  } sm;

  // load block state: X rows, neighbor lists
  {
    const int r = t >> 5, j0 = (t & 31) * 4;
    *(float4*)&Xs[r][j0] = *(const float4*)&p.Xg[(size_t)(r0 + r) * H + j0];
    for (int j = t; j < 16 * CAP; j += BLK) (&NIs[0][0])[j] = p.NI[r0 * CAP + j];
    if (t < 16) NCs[t] = p.NC[r0 + t];
  }

  auto stage_x = [&](const float* sc, const float* bi, bool do_ln) {
    const int r = t >> 5, j0 = (t & 31) * 4;
    const float4 xv = *(const float4*)&Xs[r][j0];
    float v0 = xv.x, v1 = xv.y, v2 = xv.z, v3 = xv.w;
    if (do_ln) {
      float s = v0 + v1 + v2 + v3;
      float ss = v0 * v0 + v1 * v1 + v2 * v2 + v3 * v3;
#pragma unroll
      for (int off = 1; off <= 16; off <<= 1) {
        s += __shfl_xor(s, off); ss += __shfl_xor(ss, off);
      }
      const float mean = s * (1.f / 128.f);
      const float rstd = rsqrtf(ss * (1.f / 128.f) - mean * mean + 1e-5f);
      v0 = (v0 - mean) * rstd * sc[j0]     + bi[j0];
      v1 = (v1 - mean) * rstd * sc[j0 + 1] + bi[j0 + 1];
      v2 = (v2 - mean) * rstd * sc[j0 + 2] + bi[j0 + 2];
      v3 = (v3 - mean) * rstd * sc[j0 + 3] + bi[j0 + 3];
    }
    uint2 pk;
    pk.x = (unsigned)f2bf(v0) | ((unsigned)f2bf(v1) << 16);
    pk.y = (unsigned)f2bf(v2) | ((unsigned)f2bf(v3) << 16);
    *(uint2*)&sm.g.A16[r][j0] = pk;
  };
  __syncthreads();

  // --- attention: 128 (q,h) pairs, 4 threads/pair over neighbors ---
  {
    const int pr = t >> 2, sub = t & 3;
    const int lq = pr >> 3, h = pr & 7;
    const u16* qp = qsrc + (size_t)(r0 + lq) * 384 + h * 16;
    float qv[16];
    { uint4 a = *(const uint4*)qp, b = *(const uint4*)(qp + 8);
      unpack8(a, qv); unpack8(b, qv + 8); }
#pragma unroll
    for (int d = 0; d < 16; ++d) qv[d] *= 0.25f;        // 1/sqrt(HD)
    float o[16];
#pragma unroll
    for (int d = 0; d < 16; ++d) o[d] = 0.f;
    float se = 0.f;
    const int cnt = NCs[lq];
    for (int i = sub; i < cnt; i += 4) {
      const int nb = NIs[lq][i];
      const u16* kp = qsrc + (size_t)nb * 384 + 128 + h * 16;
      float kv[16], vv[16];
      { uint4 a = *(const uint4*)kp;         uint4 b = *(const uint4*)(kp + 8);
        unpack8(a, kv); unpack8(b, kv + 8); }
      { uint4 a = *(const uint4*)(kp + 128); uint4 b = *(const uint4*)(kp + 136);
        unpack8(a, vv); unpack8(b, vv + 8); }
      float s0 = 0.f, s1 = 0.f, s2 = 0.f, s3 = 0.f;
#pragma unroll
      for (int d = 0; d < 16; d += 4) {
        s0 += qv[d] * kv[d];         s1 += qv[d + 1] * kv[d + 1];
        s2 += qv[d + 2] * kv[d + 2]; s3 += qv[d + 3] * kv[d + 3];
      }
      const float e = expf((s0 + s1) + (s2 + s3));      // |s|<~0.5, no max-sub
      se += e;
#pragma unroll
      for (int d = 0; d < 16; ++d) o[d] += e * vv[d];
    }
#pragma unroll
    for (int d = 0; d < 16; ++d) o[d] += __shfl_xor(o[d], 1);
    se += __shfl_xor(se, 1);
#pragma unroll
    for (int d = 0; d < 16; ++d) o[d] += __shfl_xor(o[d], 2);
    se += __shfl_xor(se, 2);
    if (sub == 0) {
      const float inv = 1.f / se;
      uint4 w0, w1;
      w0.x = (unsigned)f2bf(o[0] * inv)  | ((unsigned)f2bf(o[1] * inv) << 16);
      w0.y = (unsigned)f2bf(o[2] * inv)  | ((unsigned)f2bf(o[3] * inv) << 16);
      w0.z = (unsigned)f2bf(o[4] * inv)  | ((unsigned)f2bf(o[5] * inv) << 16);
      w0.w = (unsigned)f2bf(o[6] * inv)  | ((unsigned)f2bf(o[7] * inv) << 16);
      w1.x = (unsigned)f2bf(o[8] * inv)  | ((unsigned)f2bf(o[9] * inv) << 16);
      w1.y = (unsigned)f2bf(o[10] * inv) | ((unsigned)f2bf(o[11] * inv) << 16);
      w1.z = (unsigned)f2bf(o[12] * inv) | ((unsigned)f2bf(o[13] * inv) << 16);
      w1.w = (unsigned)f2bf(o[14] * inv) | ((unsigned)f2bf(o[15] * inv) << 16);
      *(uint4*)&sm.g.A16[lq][h * 16]     = w0;
      *(uint4*)&sm.g.A16[lq][h * 16 + 8] = w1;
    }
  }
  __syncthreads();
  // --- ao GEMM + residual ---
  {
    const u16* Bw = p.W + OFF_AO + l * 16384;
    const float* ab = p.ao_b + l * 128;
    const int col = w * 16 + lr;
    floatx4 acc = FZ;
#pragma unroll
    for (int k0 = 0; k0 < 128; k0 += 32) {
      short8_t a = *(const short8_t*)&sm.g.A16[lr][k0 + quad * 8];
      short8_t b = *(const short8_t*)&Bw[(size_t)col * 128 + k0 + quad * 8];
      acc = __builtin_amdgcn_mfma_f32_16x16x32_bf16(a, b, acc, 0, 0, 0);
    }
    const float bv = ab[col];
#pragma unroll
    for (int r = 0; r < 4; ++r)
      Xs[quad * 4 + r][col] += acc[r] + bv;
  }
  __syncthreads();
  // --- LN2 -> f1 (relu) -> FF1 ---
  stage_x(p.ln2_s + l * 128, p.ln2_b + l * 128, true);
  __syncthreads();
  {
    const u16* Bw = p.W + OFF_F1 + l * 32768;
    const float* fb = p.f1_b + l * 256;
    const int c0 = w * 32;
    floatx4 a0 = FZ, a1 = FZ;
#pragma unroll
    for (int k0 = 0; k0 < 128; k0 += 32) {
      short8_t a  = *(const short8_t*)&sm.g.A16[lr][k0 + quad * 8];
      short8_t b0 = *(const short8_t*)&Bw[(size_t)(c0 + lr) * 128 + k0 + quad * 8];
      short8_t b1 = *(const short8_t*)&Bw[(size_t)(c0 + 16 + lr) * 128 + k0 + quad * 8];
      a0 = __builtin_amdgcn_mfma_f32_16x16x32_bf16(a, b0, a0, 0, 0, 0);
      a1 = __builtin_amdgcn_mfma_f32_16x16x32_bf16(a, b1, a1, 0, 0, 0);
    }
#pragma unroll
    for (int r = 0; r < 4; ++r) {
      const int row = quad * 4 + r;
      sm.g.FF1[row][c0 + lr]      = f2bf(fmaxf(a0[r] + fb[c0 + lr], 0.f));
      sm.g.FF1[row][c0 + 16 + lr] = f2bf(fmaxf(a1[r] + fb[c0 + 16 + lr], 0.f));
    }
  }
  __syncthreads();
  // --- f2 + residual ---
  {
    const u16* Bw = p.W + OFF_F2 + l * 32768;
    const float* fb = p.f2_b + l * 128;
    const int col = w * 16 + lr;
    floatx4 acc = FZ;
#pragma unroll
    for (int k0 = 0; k0 < 256; k0 += 32) {
      short8_t a = *(const short8_t*)&sm.g.FF1[lr][k0 + quad * 8];
      short8_t b = *(const short8_t*)&Bw[(size_t)col * 256 + k0 + quad * 8];
      acc = __builtin_amdgcn_mfma_f32_16x16x32_bf16(a, b, acc, 0, 0, 0);
    }
    const float bv = fb[col];
#pragma unroll
    for (int r = 0; r < 4; ++r)
      Xs[quad * 4 + r][col] += acc[r] + bv;
  }
  __syncthreads();
  if (l < 3) {
    // write X back for next kernel, then LN1(l+1) + qkv(l+1)
    {
      const int r = t >> 5, j0 = (t & 31) * 4;
      *(float4*)&p.Xg[(size_t)(r0 + r) * H + j0] = *(const float4*)&Xs[r][j0];
    }
    stage_x(p.ln1_s + (l + 1) * 128, p.ln1_b + (l + 1) * 128, true);
    __syncthreads();
    {
      const u16* Bw = p.W + OFF_QKV + (l + 1) * 49152;
      const float* qb = p.qkv_b + (l + 1) * 384;
      const int c0 = w * 48;
      floatx4 a0 = FZ, a1 = FZ, a2 = FZ;
#pragma unroll
      for (int k0 = 0; k0 < 128; k0 += 32) {
        short8_t a  = *(const short8_t*)&sm.g.A16[lr][k0 + quad * 8];
        short8_t b0 = *(const short8_t*)&Bw[(size_t)(c0 + lr) * 128 + k0 + quad * 8];
        short8_t b1 = *(const short8_t*)&Bw[(size_t)(c0 + 16 + lr) * 128 + k0 + quad * 8];
        short8_t b2 = *(const short8_t*)&Bw[(size_t)(c0 + 32 + lr) * 128 + k0 + quad * 8];
        a0 = __builtin_amdgcn_mfma_f32_16x16x32_bf16(a, b0, a0, 0, 0, 0);
        a1 = __builtin_amdgcn_mfma_f32_16x16x32_bf16(a, b1, a1, 0, 0, 0);
        a2 = __builtin_amdgcn_mfma_f32_16x16x32_bf16(a, b2, a2, 0, 0, 0);
      }
      __syncthreads();
#pragma unroll
      for (int r = 0; r < 4; ++r) {
        const int row = quad * 4 + r;
        sm.QS[row][c0 + lr]      = f2bf(a0[r] + qb[c0 + lr]);
        sm.QS[row][c0 + 16 + lr] = f2bf(a1[r] + qb[c0 + 16 + lr]);
        sm.QS[row][c0 + 32 + lr] = f2bf(a2[r] + qb[c0 + 32 + lr]);
      }
      __syncthreads();
      unsigned long long* d64 = (unsigned long long*)(qdst + (size_t)r0 * 384);
      const unsigned long long* s64 = (const unsigned long long*)&sm.QS[0][0];
      for (int j = t; j < 1536; j += BLK) d64[j] = s64[j];
    }
  } else {
    // --- heads: [lat1|b1] (N=192) -> lat2+normalize, beta ---
    stage_x(nullptr, nullptr, false);
    __syncthreads();
    {
      const int c0 = w * 32;
      if (c0 < 192) {
        const u16* Bw = p.W + OFF_LAT1;
        floatx4 a0 = FZ, a1 = FZ;
#pragma unroll
        for (int k0 = 0; k0 < 128; k0 += 32) {
          short8_t a  = *(const short8_t*)&sm.g.A16[lr][k0 + quad * 8];
          short8_t b0 = *(const short8_t*)&Bw[(size_t)(c0 + lr) * 128 + k0 + quad * 8];
          short8_t b1 = *(const short8_t*)&Bw[(size_t)(c0 + 16 + lr) * 128 + k0 + quad * 8];
          a0 = __builtin_amdgcn_mfma_f32_16x16x32_bf16(a, b0, a0, 0, 0, 0);
          a1 = __builtin_amdgcn_mfma_f32_16x16x32_bf16(a, b1, a1, 0, 0, 0);
        }
        const int cA = c0 + lr, cB = c0 + 16 + lr;
        const float bA = cA < 128 ? p.lat1_b[cA] : p.b1_b[cA - 128];
        const float bB = cB < 128 ? p.lat1_b[cB] : p.b1_b[cB - 128];
#pragma unroll
        for (int r = 0; r < 4; ++r) {
          const int row = quad * 4 + r;
          sm.g.FF1[row][cA] = f2bf(fmaxf(a0[r] + bA, 0.f));
          sm.g.FF1[row][cB] = f2bf(fmaxf(a1[r] + bB, 0.f));
        }
      }
    }
    __syncthreads();
    if (t < 256) {
      const int r = t >> 4, c = t & 15;
      float acc = p.lat2_b[c];
      const u16* gw = p.W + OFF_LAT2 + c * 128;
      for (int k = 0; k < 128; ++k) acc += bfu(sm.g.FF1[r][k]) * bfu(gw[k]);
      float ss = acc * acc;
      ss += __shfl_xor(ss, 1); ss += __shfl_xor(ss, 2);
      ss += __shfl_xor(ss, 4); ss += __shfl_xor(ss, 8);
      p.out[NT + (size_t)(r0 + r) * 16 + c] = acc / fmaxf(sqrtf(ss), 1e-12f);
      float v = 0.f;
#pragma unroll
      for (int i = 0; i < 4; ++i)
        v += bfu(sm.g.FF1[r][128 + c * 4 + i]) * p.b2_w[c * 4 + i];
      v += __shfl_xor(v, 1); v += __shfl_xor(v, 2);
      v += __shfl_xor(v, 4); v += __shfl_xor(v, 8);
      if (c == 0) {
        v += p.b2_b[0];
        const float beta = 1.f / (1.f + expf(-v));
        p.out[r0 + r] = fminf(fmaxf(beta, 1e-6f), 1.f - 1e-6f);
      }
    }
  }
}

extern "C" void kernel_launch(void* const* d_in, const int* in_sizes, int n_in,
                              void* d_out, int out_size, void* d_ws, size_t ws_size,
                              hipStream_t stream) {
  Prm prm;
  prm.xr    = (const float*)d_in[0];
  prm.in_w  = (const float*)d_in[2];  prm.in_b  = (const float*)d_in[3];
  prm.ln1_s = (const float*)d_in[4];  prm.ln1_b = (const float*)d_in[5];
  prm.qkv_w = (const float*)d_in[6];  prm.qkv_b = (const float*)d_in[7];
  prm.ao_w  = (const float*)d_in[8];  prm.ao_b  = (const float*)d_in[9];
  prm.ln2_s = (const float*)d_in[10]; prm.ln2_b = (const float*)d_in[11];
  prm.f1_w  = (const float*)d_in[12]; prm.f1_b  = (const float*)d_in[13];
  prm.f2_w  = (const float*)d_in[14]; prm.f2_b  = (const float*)d_in[15];
  prm.lat1_w= (const float*)d_in[16]; prm.lat1_b= (const float*)d_in[17];
  prm.lat2_w= (const float*)d_in[18]; prm.lat2_b= (const float*)d_in[19];
  prm.b1_w  = (const float*)d_in[20]; prm.b1_b  = (const float*)d_in[21];
  prm.b2_w  = (const float*)d_in[22]; prm.b2_b  = (const float*)d_in[23];
  prm.out   = (float*)d_out;

  char* pw = (char*)d_ws;
  prm.W    = (u16*)pw;   pw += ((size_t)W_TOTAL * 2 + 255) & ~(size_t)255;
  prm.QKV0 = (u16*)pw;   pw += (size_t)NT * 384 * 2;
  prm.QKV1 = (u16*)pw;   pw += (size_t)NT * 384 * 2;
  prm.Xg   = (float*)pw; pw += (size_t)NT * H * 4;
  prm.NI   = (int*)pw;   pw += (size_t)NT * CAP * 4;
  prm.NC   = (int*)pw;   pw += (size_t)NT * 4;

  prep_kernel<<<GRID, BLK, 0, stream>>>(prm);
  layer_kernel<<<GRID, BLK, 0, stream>>>(prm, 0, prm.QKV0, prm.QKV1);
  layer_kernel<<<GRID, BLK, 0, stream>>>(prm, 1, prm.QKV1, prm.QKV0);
  layer_kernel<<<GRID, BLK, 0, stream>>>(prm, 2, prm.QKV0, prm.QKV1);
  layer_kernel<<<GRID, BLK, 0, stream>>>(prm, 3, prm.QKV1, nullptr);
}